// Round 2
// baseline (68.753 us; speedup 1.0000x reference)
//
#include <hip/hip_runtime.h>
#include <hip/hip_bf16.h>

// QGenModel self_diff_attention, algebraically factored (exact, fp32):
//   logits[b,n,g] = sum_d obj[b,n,d]^2 * S[g,d] - obj[b,n,d] * T[b,g,d] + bias[g]
//     S[g,d]   = sum_m W[g,m,d]
//     T[b,g,d] = sum_m W[g,m,d] * obj[b,m,d]
// then masked softmax over n, then vis[b,g,d] = sum_n w[b,n,g]*obj[b,n,d].
// O(B*N*D*G) instead of O(B*N^2*D*G); never materializes [B,N,N,D].
// All inputs/outputs are float32 per the reference (round-1 NaN showed the
// bf16 reinterpretation was wrong).

#define QB 128
#define QN 36
#define QD 512
#define QG 2

__global__ __launch_bounds__(QD) void qgen_self_diff_attn(
    const float* __restrict__ obj,   // [B, N, D]
    const float* __restrict__ W,     // [G, N*D]
    const float* __restrict__ bias,  // [G]
    const int* __restrict__ mask,    // [B, N] (0/1)
    float* __restrict__ out)         // [B, G*D]
{
    __shared__ float s_T[QG][QD];    // 4 KiB
    __shared__ float s_S[QG][QD];    // 4 KiB
    __shared__ float s_logit[QG][QN];
    __shared__ float s_w[QG][QN];

    const int b = blockIdx.x;
    const int t = threadIdx.x;       // 0..511 == d index
    const int wave = t >> 6;
    const int lane = t & 63;

    const float* ob = obj + (size_t)b * QN * QD;

    // ---- Pass 1: load obj[b][m][t] into registers; accumulate T, S ----
    float o[QN];
    float T0 = 0.f, T1 = 0.f, S0 = 0.f, S1 = 0.f;
    #pragma unroll
    for (int m = 0; m < QN; ++m) {
        o[m] = ob[m * QD + t];                       // coalesced
        float w0 = W[0 * QN * QD + m * QD + t];
        float w1 = W[1 * QN * QD + m * QD + t];
        T0 = fmaf(w0, o[m], T0);  T1 = fmaf(w1, o[m], T1);
        S0 += w0;                 S1 += w1;
    }
    s_T[0][t] = T0;  s_T[1][t] = T1;
    s_S[0][t] = S0;  s_S[1][t] = S1;
    __syncthreads();

    // ---- Pass 2: logits[n][g]; wave `wave` handles n = wave, wave+8, ... ----
    for (int n = wave; n < QN; n += 8) {
        float a0 = 0.f, a1 = 0.f;
        #pragma unroll
        for (int k = 0; k < QD / 64; ++k) {
            int d = lane + k * 64;
            float ov = ob[n * QD + d];               // L1/L2-hot re-read
            float oo = ov * ov;
            a0 += oo * s_S[0][d] - ov * s_T[0][d];
            a1 += oo * s_S[1][d] - ov * s_T[1][d];
        }
        #pragma unroll
        for (int off = 32; off; off >>= 1) {
            a0 += __shfl_down(a0, off);
            a1 += __shfl_down(a1, off);
        }
        if (lane == 0) {
            bool mk = mask[b * QN + n] != 0;
            s_logit[0][n] = mk ? a0 + bias[0] : -1e10f;
            s_logit[1][n] = mk ? a1 + bias[1] : -1e10f;
        }
    }
    __syncthreads();

    // ---- Pass 3: masked softmax over n, one wave per glimpse ----
    if (wave < QG) {
        float v = (lane < QN) ? s_logit[wave][lane] : -1e30f;
        float mx = v;
        #pragma unroll
        for (int off = 32; off; off >>= 1)
            mx = fmaxf(mx, __shfl_xor(mx, off));
        float e = (lane < QN) ? __expf(v - mx) : 0.f;
        float sum = e;
        #pragma unroll
        for (int off = 32; off; off >>= 1)
            sum += __shfl_xor(sum, off);
        if (lane < QN) s_w[wave][lane] = e / sum;
    }
    __syncthreads();

    // ---- Pass 4: vis[g][d] = sum_n w[g][n] * obj[n][d] (obj from registers) ----
    float v0 = 0.f, v1 = 0.f;
    #pragma unroll
    for (int n = 0; n < QN; ++n) {
        v0 = fmaf(s_w[0][n], o[n], v0);
        v1 = fmaf(s_w[1][n], o[n], v1);
    }
    out[(size_t)b * QG * QD + 0 * QD + t] = v0;
    out[(size_t)b * QG * QD + 1 * QD + t] = v1;
}

extern "C" void kernel_launch(void* const* d_in, const int* in_sizes, int n_in,
                              void* d_out, int out_size, void* d_ws, size_t ws_size,
                              hipStream_t stream) {
    const float* obj  = (const float*)d_in[0];
    const float* W    = (const float*)d_in[1];
    const float* bias = (const float*)d_in[2];
    const int*   mask = (const int*)d_in[3];
    float* out = (float*)d_out;

    qgen_self_diff_attn<<<QB, QD, 0, stream>>>(obj, W, bias, mask, out);
}

// Round 3
// 67.575 us; speedup vs baseline: 1.0174x; 1.0174x over previous
//
#include <hip/hip_runtime.h>
#include <hip/hip_bf16.h>

// QGenModel self_diff_attention, algebraically factored (exact, fp32):
//   logits[b,n,g] = sum_d obj[b,n,d]^2 * S[g,d] - obj[b,n,d] * T[b,g,d] + bias[g]
//     S[g,d]   = sum_m W[g,m,d]
//     T[b,g,d] = sum_m W[g,m,d] * obj[b,m,d]
// masked softmax over n, then vis[b,g,d] = sum_n w[b,n,g]*obj[b,n,d].
//
// Round-3 change: one block per (batch, glimpse) pair -> grid 256 (all CUs
// busy, was 128 = half idle). Mapping b = bid&127, g = bid>>7 puts both
// glimpse-blocks of a batch on the same XCD (128 % 8 == 0) so the second
// obj read hits that XCD's L2.

#define QB 128
#define QN 36
#define QD 512
#define QG 2

__global__ __launch_bounds__(QD) void qgen_self_diff_attn(
    const float* __restrict__ obj,   // [B, N, D]
    const float* __restrict__ W,     // [G, N*D]
    const float* __restrict__ bias,  // [G]
    const int* __restrict__ mask,    // [B, N] (0/1)
    float* __restrict__ out)         // [B, G*D]
{
    __shared__ float s_T[QD];        // 2 KiB
    __shared__ float s_S[QD];        // 2 KiB
    __shared__ float s_logit[QN];
    __shared__ float s_w[QN];

    const int bid = blockIdx.x;
    const int b = bid & (QB - 1);    // batch
    const int g = bid >> 7;          // glimpse
    const int t = threadIdx.x;       // 0..511 == d index
    const int wave = t >> 6;
    const int lane = t & 63;

    const float* ob = obj + (size_t)b * QN * QD;
    const float* wg = W + (size_t)g * QN * QD;

    // ---- Pass 1: load obj[b][m][t] into registers; accumulate T, S ----
    float o[QN];
    float T = 0.f, S = 0.f;
    #pragma unroll
    for (int m = 0; m < QN; ++m) {
        o[m] = ob[m * QD + t];                       // coalesced
        float w = wg[m * QD + t];
        T = fmaf(w, o[m], T);
        S += w;
    }
    s_T[t] = T;
    s_S[t] = S;
    __syncthreads();

    // ---- Pass 2: logits[n]; wave `wave` handles n = wave, wave+8, ... ----
    for (int n = wave; n < QN; n += 8) {
        float a = 0.f;
        #pragma unroll
        for (int k = 0; k < QD / 64; ++k) {
            int d = lane + k * 64;
            float ov = ob[n * QD + d];               // L2-hot re-read
            a += ov * ov * s_S[d] - ov * s_T[d];
        }
        #pragma unroll
        for (int off = 32; off; off >>= 1)
            a += __shfl_down(a, off);
        if (lane == 0) {
            bool mk = mask[b * QN + n] != 0;
            s_logit[n] = mk ? a + bias[g] : -1e10f;
        }
    }
    __syncthreads();

    // ---- Pass 3: masked softmax over n, wave 0 only ----
    if (wave == 0) {
        float v = (lane < QN) ? s_logit[lane] : -1e30f;
        float mx = v;
        #pragma unroll
        for (int off = 32; off; off >>= 1)
            mx = fmaxf(mx, __shfl_xor(mx, off));
        float e = (lane < QN) ? __expf(v - mx) : 0.f;
        float sum = e;
        #pragma unroll
        for (int off = 32; off; off >>= 1)
            sum += __shfl_xor(sum, off);
        if (lane < QN) s_w[lane] = e / sum;
    }
    __syncthreads();

    // ---- Pass 4: vis[d] = sum_n w[n] * obj[n][d] (obj from registers) ----
    float v = 0.f;
    #pragma unroll
    for (int n = 0; n < QN; ++n)
        v = fmaf(s_w[n], o[n], v);
    out[(size_t)b * QG * QD + (size_t)g * QD + t] = v;
}

extern "C" void kernel_launch(void* const* d_in, const int* in_sizes, int n_in,
                              void* d_out, int out_size, void* d_ws, size_t ws_size,
                              hipStream_t stream) {
    const float* obj  = (const float*)d_in[0];
    const float* W    = (const float*)d_in[1];
    const float* bias = (const float*)d_in[2];
    const int*   mask = (const int*)d_in[3];
    float* out = (float*)d_out;

    qgen_self_diff_attn<<<QB * QG, QD, 0, stream>>>(obj, W, bias, mask, out);
}